// Round 5
// baseline (131.272 us; speedup 1.0000x reference)
//
#include <hip/hip_runtime.h>
#include <hip/hip_bf16.h>

#define D 128

typedef __attribute__((ext_vector_type(8))) short bf16x8;
typedef __attribute__((ext_vector_type(4))) float f32x4;

// float -> bf16 bits, round-to-nearest-even
__device__ __forceinline__ unsigned short f2bf(float f) {
    union { float f; unsigned u; } uf{f};
    unsigned r = uf.u + 0x7fffu + ((uf.u >> 16) & 1u);
    return (unsigned short)(r >> 16);
}
__device__ __forceinline__ unsigned pack2(float a, float b) {
    return (unsigned)f2bf(a) | ((unsigned)f2bf(b) << 16);
}
__device__ __forceinline__ float bflo(unsigned u) {
    union { unsigned u; float f; } c{u << 16};
    return c.f;
}
__device__ __forceinline__ float bfhi(unsigned u) {
    union { unsigned u; float f; } c{u & 0xffff0000u};
    return c.f;
}

#define FMA8(A, vv, u) \
    A[0] = fmaf(vv, bflo(u.x), A[0]); A[1] = fmaf(vv, bfhi(u.x), A[1]); \
    A[2] = fmaf(vv, bflo(u.y), A[2]); A[3] = fmaf(vv, bfhi(u.y), A[3]); \
    A[4] = fmaf(vv, bflo(u.z), A[4]); A[5] = fmaf(vv, bfhi(u.z), A[5]); \
    A[6] = fmaf(vv, bflo(u.w), A[6]); A[7] = fmaf(vv, bfhi(u.w), A[7]);

// ---------------------------------------------------------------------------
// Kernel 0: rowptr[r] = (start,end) from sorted adj_rows; empty rows filled
//           from the gaps (no memset needed). Also converts W to bf16.
// ---------------------------------------------------------------------------
__global__ __launch_bounds__(256) void build_rowptr(const int* __restrict__ rows,
                                                    const float* __restrict__ W,
                                                    unsigned short* __restrict__ wbf,
                                                    int2* __restrict__ rowptr,
                                                    int e, int n) {
    int i = blockIdx.x * 256 + threadIdx.x;
    if (i < D * D) wbf[i] = f2bf(W[i]);
    if (i >= e) return;
    int r = rows[i];
    int prev = (i == 0) ? -1 : rows[i - 1];
    int next = (i == e - 1) ? n : rows[i + 1];
    if (prev != r) {
        rowptr[r].x = i;
        for (int q = prev + 1; q < r; ++q) rowptr[q] = make_int2(i, i);   // empty rows
    }
    if (next != r) {
        rowptr[r].y = i + 1;
        if (i == e - 1)
            for (int q = r + 1; q < n; ++q) rowptr[q] = make_int2(e, e); // trailing empties
    }
}

// ---------------------------------------------------------------------------
// Kernel 1: wi = bf16(x @ W^T) via MFMA, SWAPPED operands: D = W · x^T.
//   A-frag = W row (output channel), B-frag = x row (node). D layout then puts
//   4 consecutive channels in each lane's 4 acc regs -> 8B uint2 stores.
// ---------------------------------------------------------------------------
__global__ __launch_bounds__(256) void gemm_mfma(const float* __restrict__ x,
                                                 const unsigned short* __restrict__ wbf,
                                                 unsigned short* __restrict__ wi,
                                                 int nrows) {
    const int lane = threadIdx.x & 63;
    const int row0 = blockIdx.x * 128 + (threadIdx.x >> 6) * 32;  // wave's 32 nodes
    const int lrow = lane & 15;
    const int lk8 = (lane >> 4) * 8;

    // x fragments (B operand): node = row0 + xb*16 + lrow, k = kb*32 + lk8
    bf16x8 xfrag[2][4];
#pragma unroll
    for (int xb = 0; xb < 2; ++xb)
#pragma unroll
        for (int kb = 0; kb < 4; ++kb) {
            int gr = min(row0 + xb * 16 + lrow, nrows - 1);
            const float4* p = (const float4*)(x + (size_t)gr * D + kb * 32 + lk8);
            float4 f0 = p[0], f1 = p[1];
            union { bf16x8 v; unsigned u[4]; } cv;
            cv.u[0] = pack2(f0.x, f0.y);
            cv.u[1] = pack2(f0.z, f0.w);
            cv.u[2] = pack2(f1.x, f1.y);
            cv.u[3] = pack2(f1.z, f1.w);
            xfrag[xb][kb] = cv.v;
        }

    f32x4 acc[2][8];   // [xb][cb]
#pragma unroll
    for (int xb = 0; xb < 2; ++xb)
#pragma unroll
        for (int cb = 0; cb < 8; ++cb)
            acc[xb][cb] = (f32x4){0.f, 0.f, 0.f, 0.f};

#pragma unroll
    for (int cb = 0; cb < 8; ++cb) {
#pragma unroll
        for (int kb = 0; kb < 4; ++kb) {
            // A operand: W row (channel) = cb*16 + lrow, k = kb*32 + lk8
            bf16x8 wfrag = *(const bf16x8*)(wbf + (cb * 16 + lrow) * 128 + kb * 32 + lk8);
            acc[0][cb] = __builtin_amdgcn_mfma_f32_16x16x32_bf16(wfrag, xfrag[0][kb], acc[0][cb], 0, 0, 0);
            acc[1][cb] = __builtin_amdgcn_mfma_f32_16x16x32_bf16(wfrag, xfrag[1][kb], acc[1][cb], 0, 0, 0);
        }
    }

    // D layout: col(lane&15) = node-within-tile, row((lane>>4)*4+j) = channel
#pragma unroll
    for (int xb = 0; xb < 2; ++xb) {
        int g = row0 + xb * 16 + lrow;
        if (g < nrows) {
#pragma unroll
            for (int cb = 0; cb < 8; ++cb) {
                uint2 o;
                o.x = pack2(acc[xb][cb][0], acc[xb][cb][1]);
                o.y = pack2(acc[xb][cb][2], acc[xb][cb][3]);
                *(uint2*)(wi + (size_t)g * D + cb * 16 + (lane >> 4) * 4) = o;
            }
        }
    }
}

// ---------------------------------------------------------------------------
// Kernel 2: out[r] = relu(bias + sum vals[e]*wi[cols[e]])  (wi is bf16)
//   2 rows per wave interleaved -> 8 independent uint4 gathers in flight.
//   Edge idx/val loaded directly per quad-group (no shfl on the chain).
// ---------------------------------------------------------------------------
__global__ __launch_bounds__(256) void spmm_relu(const unsigned short* __restrict__ wi,
                                                 const int2* __restrict__ rowptr,
                                                 const int* __restrict__ cols,
                                                 const float* __restrict__ vals,
                                                 const float* __restrict__ bias,
                                                 float* __restrict__ out,
                                                 int n) {
    const int lane = threadIdx.x & 63;
    const int w = blockIdx.x * 4 + (threadIdx.x >> 6);
    const int rA = w * 2;
    if (rA >= n) return;
    const bool has2 = (rA + 1 < n);

    int2 rpA, rpB;
    if (has2) {
        int4 rp = *(const int4*)(rowptr + rA);      // rA even -> 16B aligned
        rpA = make_int2(rp.x, rp.y);
        rpB = make_int2(rp.z, rp.w);
    } else {
        rpA = rowptr[rA];
        rpB = make_int2(0, 0);
    }

    const int ch = (lane & 15) * 8;   // channel base this lane gathers
    const int sub = lane >> 4;        // which edge of each quad

    float a[8] = {0.f, 0.f, 0.f, 0.f, 0.f, 0.f, 0.f, 0.f};
    float b[8] = {0.f, 0.f, 0.f, 0.f, 0.f, 0.f, 0.f, 0.f};

    int baseA = rpA.x, baseB = rpB.x;
    const int eA = rpA.y, eB = rpB.y;

    while (baseA < eA || baseB < eB) {
        int cA[4], cB[4];
        float vA[4], vB[4];
#pragma unroll
        for (int p = 0; p < 4; ++p) {
            int iA = baseA + p * 4 + sub;
            int iB = baseB + p * 4 + sub;
            bool okA = iA < eA, okB = iB < eB;
            int jA = okA ? iA : 0;
            int jB = okB ? iB : 0;
            cA[p] = okA ? cols[jA] : 0;           // dummy gathers target row 0 (L1)
            vA[p] = okA ? vals[jA] : 0.f;
            cB[p] = okB ? cols[jB] : 0;
            vB[p] = okB ? vals[jB] : 0.f;
        }
        uint4 uA[4], uB[4];
#pragma unroll
        for (int p = 0; p < 4; ++p) uA[p] = *(const uint4*)(wi + (size_t)cA[p] * D + ch);
#pragma unroll
        for (int p = 0; p < 4; ++p) uB[p] = *(const uint4*)(wi + (size_t)cB[p] * D + ch);
#pragma unroll
        for (int p = 0; p < 4; ++p) {
            FMA8(a, vA[p], uA[p]);
            FMA8(b, vB[p], uB[p]);
        }
        baseA += 16;
        baseB += 16;
    }

    // xor-reduce across the 4 sub-groups; lanes 0-15 keep row A, 16-31 row B
    float r[8];
#pragma unroll
    for (int t = 0; t < 8; ++t) {
        float sA = a[t];
        sA += __shfl_xor(sA, 16);
        sA += __shfl_xor(sA, 32);
        float sB = b[t];
        sB += __shfl_xor(sB, 16);
        sB += __shfl_xor(sB, 32);
        r[t] = (lane < 16) ? sA : sB;
    }

    const int myrow = rA + (lane >> 4);            // lanes 0-15 -> rA, 16-31 -> rA+1
    if (lane < 32 && myrow < n) {
        const int cb = (lane & 15) * 8;
        float4 b0 = *(const float4*)(bias + cb);
        float4 b1 = *(const float4*)(bias + cb + 4);
        float4 o0, o1;
        o0.x = fmaxf(r[0] + b0.x, 0.f);
        o0.y = fmaxf(r[1] + b0.y, 0.f);
        o0.z = fmaxf(r[2] + b0.z, 0.f);
        o0.w = fmaxf(r[3] + b0.w, 0.f);
        o1.x = fmaxf(r[4] + b1.x, 0.f);
        o1.y = fmaxf(r[5] + b1.y, 0.f);
        o1.z = fmaxf(r[6] + b1.z, 0.f);
        o1.w = fmaxf(r[7] + b1.w, 0.f);
        *(float4*)(out + (size_t)myrow * D + cb) = o0;
        *(float4*)(out + (size_t)myrow * D + cb + 4) = o1;
    }
}

// ---------------------------------------------------------------------------
extern "C" void kernel_launch(void* const* d_in, const int* in_sizes, int n_in,
                              void* d_out, int out_size, void* d_ws, size_t ws_size,
                              hipStream_t stream) {
    const float* x        = (const float*)d_in[0];
    const int*   adj_rows = (const int*)d_in[1];
    const int*   adj_cols = (const int*)d_in[2];
    const float* adj_vals = (const float*)d_in[3];
    const float* weight   = (const float*)d_in[4];
    const float* bias     = (const float*)d_in[5];
    float*       out      = (float*)d_out;

    const int n = in_sizes[0] / D;   // 100000
    const int e = in_sizes[1];       // 1600000

    // workspace layout
    unsigned short* wi = (unsigned short*)d_ws;                 // n*128 bf16 = 25.6 MB
    size_t off = ((size_t)n * D * sizeof(unsigned short) + 255) & ~(size_t)255;
    int2* rowptr = (int2*)((char*)d_ws + off);                  // n int2 = 0.8 MB
    unsigned short* wbf = (unsigned short*)(rowptr + n);        // 32 KB bf16 W

    build_rowptr<<<(e + 255) / 256, 256, 0, stream>>>(adj_rows, weight, wbf,
                                                      rowptr, e, n);

    gemm_mfma<<<(n + 127) / 128, 256, 0, stream>>>(x, wbf, wi, n);

    const int nwaves = (n + 1) / 2;
    spmm_relu<<<(nwaves + 3) / 4, 256, 0, stream>>>(wi, rowptr, adj_cols, adj_vals,
                                                    bias, out, n);
}